// Round 8
// baseline (34.143 us; speedup 1.0000x reference)
//
#include <hip/hip_runtime.h>

// out[b,o] = sum_h W2[o,h]*leaky(h) + b2[o],  h = W1[o]·x[b] + b1[o]
// leaky(t) = 0.6t + 0.4|t|
//   out[b,o] = 0.6(v[o]·x[b] + c0[o]) + b2[o] + sum_h (0.4 W2[o,h])|h|
// R8: everything on v_mfma_f32_16x16x16_f16 (K=16 EXACT, no padding):
//   stage1 swapped: d = mfma16(A=W1frag, B=xfrag, C=b1 f32 bcast)
//     lane's d[r] = h[ct*16 + kg*4+r] for b=col  == stage2 A-layout exactly.
//   stage2: acc = mfma16(A=cvt(|d|), B=0.4*W2 bcast, acc)   (2 cvt only)
//   init:   acc = mfma16(A=xfrag, B=0.6v bcast, C=(0.6c0+b2) bcast)
// Per 16x16h tile-step: 2 MFMA + 2 VALU. 8 b-tiles/wave, A1+W2 fused in one
// b128 LDS read per ct. 1024 blocks x 256thr, 4 blocks/CU all-resident.

#define B_DIM 32768
#define I_DIM 16
#define O_DIM 16
#define H_DIM 512

typedef _Float16 f16x4 __attribute__((ext_vector_type(4)));
typedef _Float16 f16x8 __attribute__((ext_vector_type(8)));
typedef __fp16   h16x2 __attribute__((ext_vector_type(2)));   // cvt_pkrtz native
typedef float    f32x4 __attribute__((ext_vector_type(4)));
typedef int      i32x2 __attribute__((ext_vector_type(2)));

// ws layout (bytes)
#define AW_OFF   0                   // [16 o][32 ct][64 l][A1:4f16|W2:4f16] = 512 KiB
#define VL_OFF   (512 * 1024)        // [16 o][64 l][4 f16] = 8 KiB
#define C0_OFF   (522 * 1024)        // 16 floats
#define XH2_OFF  (528 * 1024)        // [2048 tile][64 l][4 f16] = 1 MiB

// --- prep -------------------------------------------------------------------
// blk [0,128)  : W1/W2 -> fused AW fragments
// blk [128,640): x -> xh2 fragment layout (f16)
// blk [640,656): v, c0 -> vlin + c0b2
__global__ void prep_all(const float* __restrict__ W1, const float* __restrict__ b1,
                         const float* __restrict__ W2, const float* __restrict__ b2,
                         const float* __restrict__ x,
                         ushort* __restrict__ aw, ushort* __restrict__ xh2,
                         ushort* __restrict__ vl, float* __restrict__ c0b2) {
    int blk = blockIdx.x;
    if (blk < 128) {
        // t = [o][ct][lane]; lane: row=l&15 (h_lo), kg=l>>4 (k-group)
        int t = blk * 256 + threadIdx.x;
        int l = t & 63, ct = (t >> 6) & 31, o = t >> 11;
        int row = l & 15, kg = l >> 4;
        f16x8 v;
#pragma unroll
        for (int j = 0; j < 4; ++j)
            v[j] = (_Float16)W1[(size_t)(o * H_DIM + ct * 16 + row) * I_DIM + kg * 4 + j];
#pragma unroll
        for (int j = 0; j < 4; ++j)
            v[4 + j] = (_Float16)(0.4f * W2[o * H_DIM + ct * 16 + kg * 4 + j]);
        *reinterpret_cast<f16x8*>(aw + (size_t)t * 8) = v;
    } else if (blk < 640) {
        // t = [tile][lane]: xf[j] = x[tile*16 + (l&15)][(l>>4)*4 + j]
        int t = (blk - 128) * 256 + threadIdx.x;   // 0..131071
        int l = t & 63, tile = t >> 6;
        const float* src = x + (size_t)(tile * 16 + (l & 15)) * I_DIM + (l >> 4) * 4;
        f16x4 v;
#pragma unroll
        for (int j = 0; j < 4; ++j) v[j] = (_Float16)src[j];
        *reinterpret_cast<f16x4*>(xh2 + (size_t)t * 4) = v;
    } else {
        // per-o: v[i] = sum_h W2[h]W1[h,i];  c0 = sum_h W2[h]b1[h]
        __shared__ float red[256];
        __shared__ float v_sm[16];
        const int o = blk - 640, t = threadIdx.x;
        const int i = t & 15, hc = t >> 4;
        float acc = 0.f;
        for (int hh = 0; hh < 32; ++hh) {
            int h = hc * 32 + hh;
            acc = fmaf(W2[o * H_DIM + h], W1[(size_t)(o * H_DIM + h) * I_DIM + i], acc);
        }
        red[t] = acc;
        __syncthreads();
        if (t < 16) {
            float s = 0.f;
#pragma unroll
            for (int k = 0; k < 16; ++k) s += red[t + 16 * k];
            v_sm[t] = 0.6f * s;
        }
        float cacc = 0.f;
        for (int h = t; h < H_DIM; h += 256) cacc += W2[o * H_DIM + h] * b1[o * H_DIM + h];
        __syncthreads();
        red[t] = cacc;
        __syncthreads();
        if (t == 0) {
            float s = 0.f;
            for (int k = 0; k < 256; ++k) s += red[k];
            c0b2[o] = 0.6f * s + b2[o];
        }
        if (t < 64) {
            int kg = t >> 4;
            f16x4 v;
#pragma unroll
            for (int j = 0; j < 4; ++j) v[j] = (_Float16)v_sm[kg * 4 + j];
            *reinterpret_cast<f16x4*>(vl + (size_t)(o * 64 + t) * 4) = v;
        }
    }
}

// --- main -------------------------------------------------------------------
// 1024 blocks x 256 thr (4 waves), 4 blocks/CU (35KB LDS), all co-resident.
// o = blk&15, grp = blk>>4 (64). Wave w: 8 b-tiles, tb=(grp*4+w)*8.
__global__ __launch_bounds__(256, 4) void mlp_main(
    const ushort* __restrict__ xh2_u, const ushort* __restrict__ aw_u,
    const ushort* __restrict__ vl_u, const float* __restrict__ c0b2,
    const float* __restrict__ b1, float* __restrict__ out) {
    __shared__ f16x8 sm_aw[2048];     // [ct][lane] {A1|W2}  32 KiB
    __shared__ float sm_b1[512];      //  2 KiB
    __shared__ f16x4 sm_vl[64];       //  0.5 KiB

    const int tid = threadIdx.x;
    const int o   = blockIdx.x & 15;
    const int grp = blockIdx.x >> 4;

    const f16x8* gaw = reinterpret_cast<const f16x8*>(aw_u) + (size_t)o * 2048;
#pragma unroll
    for (int i = 0; i < 8; ++i) sm_aw[i * 256 + tid] = gaw[i * 256 + tid];
    sm_b1[tid]       = b1[o * H_DIM + tid];
    sm_b1[tid + 256] = b1[o * H_DIM + tid + 256];
    if (tid < 64) sm_vl[tid] = reinterpret_cast<const f16x4*>(vl_u)[o * 64 + tid];
    __syncthreads();

    const int lane = tid & 63, w = tid >> 6;
    const int col = lane & 15, kg = lane >> 4;
    const int tb = (grp * 4 + w) * 8;           // first of 8 b-tiles

    // x fragments: serve as stage1-B and init-A (identical lane contents)
    const f16x4* gxf = reinterpret_cast<const f16x4*>(xh2_u);
    f16x4 xf[8];
#pragma unroll
    for (int t = 0; t < 8; ++t) xf[t] = gxf[(size_t)(tb + t) * 64 + lane];

    const float c0 = c0b2[o];
    const f32x4 linC = {c0, c0, c0, c0};
    const f16x4 vlf = sm_vl[lane];
    f32x4 acc[8];
#pragma unroll
    for (int t = 0; t < 8; ++t)
        acc[t] = __builtin_amdgcn_mfma_f32_16x16x16f16(xf[t], vlf, linC, 0, 0, 0);

#pragma unroll 4
    for (int ct = 0; ct < 32; ++ct) {
        const f16x8 awv = sm_aw[ct * 64 + lane];
        const f16x4 A1  = __builtin_shufflevector(awv, awv, 0, 1, 2, 3);
        const f16x4 W2f = __builtin_shufflevector(awv, awv, 4, 5, 6, 7);
        const f32x4 bC  = *reinterpret_cast<const f32x4*>(&sm_b1[ct * 16 + kg * 4]);
#pragma unroll
        for (int t = 0; t < 8; ++t) {
            // stage1: d[r] = h[ct*16 + kg*4 + r] for b=col (bias included)
            f32x4 d = __builtin_amdgcn_mfma_f32_16x16x16f16(A1, xf[t], bC, 0, 0, 0);
            // pack |d| -> stage2 A fragment (2 VALU)
            h16x2 p0 = __builtin_amdgcn_cvt_pkrtz(fabsf(d[0]), fabsf(d[1]));
            h16x2 p1 = __builtin_amdgcn_cvt_pkrtz(fabsf(d[2]), fabsf(d[3]));
            i32x2 ai; ai[0] = __builtin_bit_cast(int, p0); ai[1] = __builtin_bit_cast(int, p1);
            f16x4 A2 = __builtin_bit_cast(f16x4, ai);
            // stage2: acc += 0.4*sum_h w2|h|  (rows of D = b)
            acc[t] = __builtin_amdgcn_mfma_f32_16x16x16f16(A2, W2f, acc[t], 0, 0, 0);
        }
    }

    // acc[t][r]: row b_local = kg*4 + r (all 16 cols identical).
    if (col < 4) {
#pragma unroll
        for (int t = 0; t < 8; ++t) {
            float v = (col == 0) ? acc[t][0] : (col == 1) ? acc[t][1]
                    : (col == 2) ? acc[t][2] : acc[t][3];
            out[(size_t)((tb + t) * 16 + kg * 4 + col) * O_DIM + o] = v;
        }
    }
}

extern "C" void kernel_launch(void* const* d_in, const int* in_sizes, int n_in,
                              void* d_out, int out_size, void* d_ws, size_t ws_size,
                              hipStream_t stream) {
    const float* x  = (const float*)d_in[0];
    const float* W1 = (const float*)d_in[1];
    const float* b1 = (const float*)d_in[2];
    const float* W2 = (const float*)d_in[3];
    const float* b2 = (const float*)d_in[4];
    float* out = (float*)d_out;
    char* ws = (char*)d_ws;

    ushort* aw   = (ushort*)(ws + AW_OFF);
    ushort* vl   = (ushort*)(ws + VL_OFF);
    float*  c0b2 = (float*)(ws + C0_OFF);
    ushort* xh2  = (ushort*)(ws + XH2_OFF);

    prep_all<<<656, 256, 0, stream>>>(W1, b1, W2, b2, x, aw, xh2, vl, c0b2);
    mlp_main<<<1024, 256, 0, stream>>>(xh2, aw, vl, c0b2, b1, out);
}

// Round 9
// 31.546 us; speedup vs baseline: 1.0823x; 1.0823x over previous
//
#include <hip/hip_runtime.h>

// out[b,o] = sum_h W2[o,h]*leaky(h) + b2[o],  h = W1[o]·x[b] + b1[o]
// leaky(t) = 0.6t + 0.4|t|
//   out[b,o] = 0.6(v[o]·x[b] + c0[o]) + b2[o] + sum_h (0.4 W2[o,h])|h|
// R9: hybrid shapes. stage1 = mfma 16x16x16 (K=16 exact, b1 rides f32 C);
// stage2 = mfma 16x16x32 (one MFMA eats TWO ct's of |h|, R6-verified w2f
// permutation). x loaded as f32x4 directly in main (x-prep pass deleted),
// folded to f16 via 2 cvt_pkrtz per tile. 1024x256, 4 blk/CU, one round.

#define B_DIM 32768
#define I_DIM 16
#define O_DIM 16
#define H_DIM 512

typedef _Float16 f16x4 __attribute__((ext_vector_type(4)));
typedef _Float16 f16x8 __attribute__((ext_vector_type(8)));
typedef __fp16   h16x2 __attribute__((ext_vector_type(2)));   // cvt_pkrtz native
typedef float    f32x4 __attribute__((ext_vector_type(4)));
typedef int      i32x2 __attribute__((ext_vector_type(2)));
typedef int      i32x4 __attribute__((ext_vector_type(4)));

// ws layout (bytes)
#define A1P_OFF  0                   // [16 o][16 p][64 l][8 f16] = 256 KiB
#define W2F_OFF  (256 * 1024)        // [16 o][16 p][64 l][8 f16] = 256 KiB
#define VL_OFF   (512 * 1024)        // [16 o][64 l][4 f16] = 8 KiB
#define C0_OFF   (521 * 1024)        // 16 floats

// --- prep -------------------------------------------------------------------
// blk [0,64)   : W1 -> paired stage1-A fragments (ct=2p | ct=2p+1)
// blk [64,128) : W2 -> stage2-B fragments (0.4-scaled, k->h permutation)
// blk [128,144): v, c0
__global__ void prep_all(const float* __restrict__ W1, const float* __restrict__ b1,
                         const float* __restrict__ W2, const float* __restrict__ b2,
                         ushort* __restrict__ a1p, ushort* __restrict__ w2f,
                         ushort* __restrict__ vl, float* __restrict__ c0b2) {
    int blk = blockIdx.x;
    if (blk < 64) {
        int t = blk * 256 + threadIdx.x;          // [o][p][lane]
        int l = t & 63, p = (t >> 6) & 15, o = t >> 10;
        int row = l & 15, kg = l >> 4;
        f16x8 v;
#pragma unroll
        for (int j = 0; j < 4; ++j)
            v[j] = (_Float16)W1[(size_t)(o * H_DIM + (2 * p) * 16 + row) * I_DIM + kg * 4 + j];
#pragma unroll
        for (int j = 0; j < 4; ++j)
            v[4 + j] = (_Float16)W1[(size_t)(o * H_DIM + (2 * p + 1) * 16 + row) * I_DIM + kg * 4 + j];
        *reinterpret_cast<f16x8*>(a1p + (size_t)t * 8) = v;
    } else if (blk < 128) {
        // B-frag x32: k=kg*8+j -> h = p*32 + ((j>>2)&1)*16 + kg*4 + (j&3)
        int t = (blk - 64) * 256 + threadIdx.x;   // [o][p][lane]
        int l = t & 63, p = (t >> 6) & 15, o = t >> 10;
        int kg = l >> 4;
        f16x8 v;
#pragma unroll
        for (int j = 0; j < 8; ++j) {
            int h = p * 32 + ((j >> 2) & 1) * 16 + kg * 4 + (j & 3);
            v[j] = (_Float16)(0.4f * W2[o * H_DIM + h]);
        }
        *reinterpret_cast<f16x8*>(w2f + (size_t)t * 8) = v;
    } else {
        // per-o: v[i] = sum_h W2[h]W1[h,i];  c0b2 = 0.6*sum_h W2[h]b1[h] + b2
        __shared__ float red[256];
        __shared__ float v_sm[16];
        const int o = blk - 128, t = threadIdx.x;
        const int i = t & 15, hc = t >> 4;
        float acc = 0.f;
        for (int hh = 0; hh < 32; ++hh) {
            int h = hc * 32 + hh;
            acc = fmaf(W2[o * H_DIM + h], W1[(size_t)(o * H_DIM + h) * I_DIM + i], acc);
        }
        red[t] = acc;
        __syncthreads();
        if (t < 16) {
            float s = 0.f;
#pragma unroll
            for (int k = 0; k < 16; ++k) s += red[t + 16 * k];
            v_sm[t] = 0.6f * s;
        }
        float cacc = 0.f;
        for (int h = t; h < H_DIM; h += 256) cacc += W2[o * H_DIM + h] * b1[o * H_DIM + h];
        __syncthreads();
        red[t] = cacc;
        __syncthreads();
        if (t == 0) {
            float s = 0.f;
            for (int k = 0; k < 256; ++k) s += red[k];
            c0b2[o] = 0.6f * s + b2[o];
        }
        if (t < 64) {
            int kg = t >> 4;
            f16x4 v;
#pragma unroll
            for (int j = 0; j < 4; ++j) v[j] = (_Float16)v_sm[kg * 4 + j];
            *reinterpret_cast<f16x4*>(vl + (size_t)(o * 64 + t) * 4) = v;
        }
    }
}

// --- main -------------------------------------------------------------------
// 1024 blocks x 256 thr (4 waves), 35 KB LDS -> 4 blocks/CU, one round.
// o = blk&15 (head pinned per XCD L2), grp = blk>>4 (64 per o).
// Wave w: 8 b-tiles, tile = grp*32 + w*8 + t.
__global__ __launch_bounds__(256, 4) void mlp_main(
    const float* __restrict__ x, const ushort* __restrict__ a1p_u,
    const ushort* __restrict__ w2f_u, const ushort* __restrict__ vl_u,
    const float* __restrict__ c0b2, const float* __restrict__ b1,
    float* __restrict__ out) {
    __shared__ f16x8 sm_a1[1024];     // [p][lane] stage1-A pairs  16 KiB
    __shared__ f16x8 sm_w2[1024];     // [p][lane] stage2-B        16 KiB
    __shared__ float sm_b1[512];      //  2 KiB
    __shared__ f16x4 sm_vl[64];       //  0.5 KiB

    const int tid = threadIdx.x;
    const int o   = blockIdx.x & 15;
    const int grp = blockIdx.x >> 4;

    const f16x8* ga = reinterpret_cast<const f16x8*>(a1p_u) + (size_t)o * 1024;
    const f16x8* gw = reinterpret_cast<const f16x8*>(w2f_u) + (size_t)o * 1024;
#pragma unroll
    for (int i = 0; i < 4; ++i) sm_a1[i * 256 + tid] = ga[i * 256 + tid];
#pragma unroll
    for (int i = 0; i < 4; ++i) sm_w2[i * 256 + tid] = gw[i * 256 + tid];
    sm_b1[tid]       = b1[o * H_DIM + tid];
    sm_b1[tid + 256] = b1[o * H_DIM + tid + 256];
    if (tid < 64) sm_vl[tid] = reinterpret_cast<const f16x4*>(vl_u)[o * 64 + tid];
    __syncthreads();

    const int lane = tid & 63, w = tid >> 6;
    const int col = lane & 15, kg = lane >> 4;
    const int tile0 = grp * 32 + w * 8;

    // x fragments: load f32x4 (coalesced 1KB/wave/tile), fold to f16 (2 cvt).
    f16x4 xf[8];
#pragma unroll
    for (int t = 0; t < 8; ++t) {
        const f32x4 xr = *reinterpret_cast<const f32x4*>(
            x + (size_t)((tile0 + t) * 16 + col) * I_DIM + kg * 4);
        h16x2 q0 = __builtin_amdgcn_cvt_pkrtz(xr[0], xr[1]);
        h16x2 q1 = __builtin_amdgcn_cvt_pkrtz(xr[2], xr[3]);
        i32x2 xi; xi[0] = __builtin_bit_cast(int, q0); xi[1] = __builtin_bit_cast(int, q1);
        xf[t] = __builtin_bit_cast(f16x4, xi);
    }

    // acc init = linear part (rows of D = b)
    const float c0 = c0b2[o];
    const f32x4 linC = {c0, c0, c0, c0};
    const f16x4 vlf = sm_vl[lane];
    f32x4 acc[8];
#pragma unroll
    for (int t = 0; t < 8; ++t)
        acc[t] = __builtin_amdgcn_mfma_f32_16x16x16f16(xf[t], vlf, linC, 0, 0, 0);

#pragma unroll 2
    for (int p = 0; p < 16; ++p) {
        const f16x8 a1pair = sm_a1[p * 64 + lane];
        const f16x4 A1a = __builtin_shufflevector(a1pair, a1pair, 0, 1, 2, 3);
        const f16x4 A1b = __builtin_shufflevector(a1pair, a1pair, 4, 5, 6, 7);
        const f16x8 W2f = sm_w2[p * 64 + lane];
        const f32x4 bC0 = *reinterpret_cast<const f32x4*>(&sm_b1[p * 32 + kg * 4]);
        const f32x4 bC1 = *reinterpret_cast<const f32x4*>(&sm_b1[p * 32 + 16 + kg * 4]);
#pragma unroll
        for (int t = 0; t < 8; ++t) {
            // stage1 (K=16 exact): d0[r] = h[p*32 + kg*4+r], d1[r] = h[p*32+16+kg*4+r]
            f32x4 d0 = __builtin_amdgcn_mfma_f32_16x16x16f16(A1a, xf[t], bC0, 0, 0, 0);
            f32x4 d1 = __builtin_amdgcn_mfma_f32_16x16x16f16(A1b, xf[t], bC1, 0, 0, 0);
            // pack |d0|,|d1| -> stage2 A (k order matches w2f permutation)
            h16x2 p0 = __builtin_amdgcn_cvt_pkrtz(fabsf(d0[0]), fabsf(d0[1]));
            h16x2 p1 = __builtin_amdgcn_cvt_pkrtz(fabsf(d0[2]), fabsf(d0[3]));
            h16x2 p2 = __builtin_amdgcn_cvt_pkrtz(fabsf(d1[0]), fabsf(d1[1]));
            h16x2 p3 = __builtin_amdgcn_cvt_pkrtz(fabsf(d1[2]), fabsf(d1[3]));
            i32x4 ai;
            ai[0] = __builtin_bit_cast(int, p0); ai[1] = __builtin_bit_cast(int, p1);
            ai[2] = __builtin_bit_cast(int, p2); ai[3] = __builtin_bit_cast(int, p3);
            f16x8 A2 = __builtin_bit_cast(f16x8, ai);
            // stage2 (K=32): acc += 0.4 * sum over 32 h of w2|h|
            acc[t] = __builtin_amdgcn_mfma_f32_16x16x32_f16(A2, W2f, acc[t], 0, 0, 0);
        }
    }

    // acc[t][r]: b_local = kg*4 + r (all 16 cols identical).
    if (col < 4) {
#pragma unroll
        for (int t = 0; t < 8; ++t) {
            float v = (col == 0) ? acc[t][0] : (col == 1) ? acc[t][1]
                    : (col == 2) ? acc[t][2] : acc[t][3];
            out[(size_t)((tile0 + t) * 16 + kg * 4 + col) * O_DIM + o] = v;
        }
    }
}

extern "C" void kernel_launch(void* const* d_in, const int* in_sizes, int n_in,
                              void* d_out, int out_size, void* d_ws, size_t ws_size,
                              hipStream_t stream) {
    const float* x  = (const float*)d_in[0];
    const float* W1 = (const float*)d_in[1];
    const float* b1 = (const float*)d_in[2];
    const float* W2 = (const float*)d_in[3];
    const float* b2 = (const float*)d_in[4];
    float* out = (float*)d_out;
    char* ws = (char*)d_ws;

    ushort* a1p  = (ushort*)(ws + A1P_OFF);
    ushort* w2f  = (ushort*)(ws + W2F_OFF);
    ushort* vl   = (ushort*)(ws + VL_OFF);
    float*  c0b2 = (float*)(ws + C0_OFF);

    prep_all<<<144, 256, 0, stream>>>(W1, b1, W2, b2, a1p, w2f, vl, c0b2);
    mlp_main<<<1024, 256, 0, stream>>>(x, a1p, w2f, vl, c0b2, b1, out);
}

// Round 10
// 31.034 us; speedup vs baseline: 1.1002x; 1.0165x over previous
//
#include <hip/hip_runtime.h>

// out[b,o] = sum_h W2[o,h]*leaky(h) + b2[o],  h = W1[o]·x[b] + b1[o]
// leaky(t) = 0.6t + 0.4|t|
//   out[b,o] = 0.6(v[o]·x[b] + c0[o]) + b2[o] + sum_h (0.4 W2[o,h])|h|
// R10 = R9 math, occupancy-doubled: 2 tiles/wave, 512-thr blocks (8 waves),
// 2048 blocks, __launch_bounds__(512,8) -> VGPR<=64 -> 8 waves/SIMD
// (m69: waves halve at 64/128; all prior rounds sat at 4/SIMD, VGPR 100-128).

#define B_DIM 32768
#define I_DIM 16
#define O_DIM 16
#define H_DIM 512

typedef _Float16 f16x4 __attribute__((ext_vector_type(4)));
typedef _Float16 f16x8 __attribute__((ext_vector_type(8)));
typedef __fp16   h16x2 __attribute__((ext_vector_type(2)));   // cvt_pkrtz native
typedef float    f32x4 __attribute__((ext_vector_type(4)));
typedef int      i32x2 __attribute__((ext_vector_type(2)));
typedef int      i32x4 __attribute__((ext_vector_type(4)));

// ws layout (bytes)
#define A1P_OFF  0                   // [16 o][16 p][64 l][8 f16] = 256 KiB
#define W2F_OFF  (256 * 1024)        // [16 o][16 p][64 l][8 f16] = 256 KiB
#define VL_OFF   (512 * 1024)        // [16 o][64 l][4 f16] = 8 KiB
#define C0_OFF   (521 * 1024)        // 16 floats

// --- prep (unchanged from R9) -----------------------------------------------
__global__ void prep_all(const float* __restrict__ W1, const float* __restrict__ b1,
                         const float* __restrict__ W2, const float* __restrict__ b2,
                         ushort* __restrict__ a1p, ushort* __restrict__ w2f,
                         ushort* __restrict__ vl, float* __restrict__ c0b2) {
    int blk = blockIdx.x;
    if (blk < 64) {
        int t = blk * 256 + threadIdx.x;          // [o][p][lane]
        int l = t & 63, p = (t >> 6) & 15, o = t >> 10;
        int row = l & 15, kg = l >> 4;
        f16x8 v;
#pragma unroll
        for (int j = 0; j < 4; ++j)
            v[j] = (_Float16)W1[(size_t)(o * H_DIM + (2 * p) * 16 + row) * I_DIM + kg * 4 + j];
#pragma unroll
        for (int j = 0; j < 4; ++j)
            v[4 + j] = (_Float16)W1[(size_t)(o * H_DIM + (2 * p + 1) * 16 + row) * I_DIM + kg * 4 + j];
        *reinterpret_cast<f16x8*>(a1p + (size_t)t * 8) = v;
    } else if (blk < 128) {
        // B-frag x32: k=kg*8+j -> h = p*32 + ((j>>2)&1)*16 + kg*4 + (j&3)
        int t = (blk - 64) * 256 + threadIdx.x;   // [o][p][lane]
        int l = t & 63, p = (t >> 6) & 15, o = t >> 10;
        int kg = l >> 4;
        f16x8 v;
#pragma unroll
        for (int j = 0; j < 8; ++j) {
            int h = p * 32 + ((j >> 2) & 1) * 16 + kg * 4 + (j & 3);
            v[j] = (_Float16)(0.4f * W2[o * H_DIM + h]);
        }
        *reinterpret_cast<f16x8*>(w2f + (size_t)t * 8) = v;
    } else {
        // per-o: v[i] = sum_h W2[h]W1[h,i];  c0b2 = 0.6*sum_h W2[h]b1[h] + b2
        __shared__ float red[256];
        __shared__ float v_sm[16];
        const int o = blk - 128, t = threadIdx.x;
        const int i = t & 15, hc = t >> 4;
        float acc = 0.f;
        for (int hh = 0; hh < 32; ++hh) {
            int h = hc * 32 + hh;
            acc = fmaf(W2[o * H_DIM + h], W1[(size_t)(o * H_DIM + h) * I_DIM + i], acc);
        }
        red[t] = acc;
        __syncthreads();
        if (t < 16) {
            float s = 0.f;
#pragma unroll
            for (int k = 0; k < 16; ++k) s += red[t + 16 * k];
            v_sm[t] = 0.6f * s;
        }
        float cacc = 0.f;
        for (int h = t; h < H_DIM; h += 256) cacc += W2[o * H_DIM + h] * b1[o * H_DIM + h];
        __syncthreads();
        red[t] = cacc;
        __syncthreads();
        if (t == 0) {
            float s = 0.f;
            for (int k = 0; k < 256; ++k) s += red[k];
            c0b2[o] = 0.6f * s + b2[o];
        }
        if (t < 64) {
            int kg = t >> 4;
            f16x4 v;
#pragma unroll
            for (int j = 0; j < 4; ++j) v[j] = (_Float16)v_sm[kg * 4 + j];
            *reinterpret_cast<f16x4*>(vl + (size_t)(o * 64 + t) * 4) = v;
        }
    }
}

// --- main -------------------------------------------------------------------
// 2048 blocks x 512 thr (8 waves), 35 KB LDS -> 4 blocks/CU, 32 waves/CU.
// o = blk&15, grp = blk>>4 (128 per o). Wave w: 2 b-tiles, tile0=grp*16+w*2.
__global__ __launch_bounds__(512, 8) void mlp_main(
    const float* __restrict__ x, const ushort* __restrict__ a1p_u,
    const ushort* __restrict__ w2f_u, const ushort* __restrict__ vl_u,
    const float* __restrict__ c0b2, const float* __restrict__ b1,
    float* __restrict__ out) {
    __shared__ f16x8 sm_a1[1024];     // [p][lane] stage1-A pairs  16 KiB
    __shared__ f16x8 sm_w2[1024];     // [p][lane] stage2-B        16 KiB
    __shared__ float sm_b1[512];      //  2 KiB
    __shared__ f16x4 sm_vl[64];       //  0.5 KiB

    const int tid = threadIdx.x;
    const int o   = blockIdx.x & 15;
    const int grp = blockIdx.x >> 4;

    const f16x8* ga = reinterpret_cast<const f16x8*>(a1p_u) + (size_t)o * 1024;
    const f16x8* gw = reinterpret_cast<const f16x8*>(w2f_u) + (size_t)o * 1024;
#pragma unroll
    for (int i = 0; i < 2; ++i) sm_a1[i * 512 + tid] = ga[i * 512 + tid];
#pragma unroll
    for (int i = 0; i < 2; ++i) sm_w2[i * 512 + tid] = gw[i * 512 + tid];
    sm_b1[tid] = b1[o * H_DIM + tid];
    if (tid < 64) sm_vl[tid] = reinterpret_cast<const f16x4*>(vl_u)[o * 64 + tid];
    __syncthreads();

    const int lane = tid & 63, w = tid >> 6;
    const int col = lane & 15, kg = lane >> 4;
    const int tile0 = grp * 16 + w * 2;

    // x fragments: f32x4 coalesced load, fold to f16 (2 cvt per tile).
    f16x4 xf[2];
#pragma unroll
    for (int t = 0; t < 2; ++t) {
        const f32x4 xr = *reinterpret_cast<const f32x4*>(
            x + (size_t)((tile0 + t) * 16 + col) * I_DIM + kg * 4);
        h16x2 q0 = __builtin_amdgcn_cvt_pkrtz(xr[0], xr[1]);
        h16x2 q1 = __builtin_amdgcn_cvt_pkrtz(xr[2], xr[3]);
        i32x2 xi; xi[0] = __builtin_bit_cast(int, q0); xi[1] = __builtin_bit_cast(int, q1);
        xf[t] = __builtin_bit_cast(f16x4, xi);
    }

    // acc init = linear part (rows of D = b)
    const float c0 = c0b2[o];
    const f32x4 linC = {c0, c0, c0, c0};
    const f16x4 vlf = sm_vl[lane];
    f32x4 acc[2];
#pragma unroll
    for (int t = 0; t < 2; ++t)
        acc[t] = __builtin_amdgcn_mfma_f32_16x16x16f16(xf[t], vlf, linC, 0, 0, 0);

#pragma unroll 2
    for (int p = 0; p < 16; ++p) {
        const f16x8 a1pair = sm_a1[p * 64 + lane];
        const f16x4 A1a = __builtin_shufflevector(a1pair, a1pair, 0, 1, 2, 3);
        const f16x4 A1b = __builtin_shufflevector(a1pair, a1pair, 4, 5, 6, 7);
        const f16x8 W2f = sm_w2[p * 64 + lane];
        const f32x4 bC0 = *reinterpret_cast<const f32x4*>(&sm_b1[p * 32 + kg * 4]);
        const f32x4 bC1 = *reinterpret_cast<const f32x4*>(&sm_b1[p * 32 + 16 + kg * 4]);
#pragma unroll
        for (int t = 0; t < 2; ++t) {
            // stage1 (K=16 exact): d0[r] = h[p*32+kg*4+r], d1[r] = h[p*32+16+kg*4+r]
            f32x4 d0 = __builtin_amdgcn_mfma_f32_16x16x16f16(A1a, xf[t], bC0, 0, 0, 0);
            f32x4 d1 = __builtin_amdgcn_mfma_f32_16x16x16f16(A1b, xf[t], bC1, 0, 0, 0);
            // pack |d0|,|d1| -> stage2 A (k order matches w2f permutation)
            h16x2 p0 = __builtin_amdgcn_cvt_pkrtz(fabsf(d0[0]), fabsf(d0[1]));
            h16x2 p1 = __builtin_amdgcn_cvt_pkrtz(fabsf(d0[2]), fabsf(d0[3]));
            h16x2 p2 = __builtin_amdgcn_cvt_pkrtz(fabsf(d1[0]), fabsf(d1[1]));
            h16x2 p3 = __builtin_amdgcn_cvt_pkrtz(fabsf(d1[2]), fabsf(d1[3]));
            i32x4 ai;
            ai[0] = __builtin_bit_cast(int, p0); ai[1] = __builtin_bit_cast(int, p1);
            ai[2] = __builtin_bit_cast(int, p2); ai[3] = __builtin_bit_cast(int, p3);
            f16x8 A2 = __builtin_bit_cast(f16x8, ai);
            // stage2 (K=32): acc += 0.4 * sum over 32 h of w2|h|
            acc[t] = __builtin_amdgcn_mfma_f32_16x16x32_f16(A2, W2f, acc[t], 0, 0, 0);
        }
    }

    // acc[t][r]: b_local = kg*4 + r (all 16 cols identical).
    if (col < 4) {
#pragma unroll
        for (int t = 0; t < 2; ++t) {
            float v = (col == 0) ? acc[t][0] : (col == 1) ? acc[t][1]
                    : (col == 2) ? acc[t][2] : acc[t][3];
            out[(size_t)((tile0 + t) * 16 + kg * 4 + col) * O_DIM + o] = v;
        }
    }
}

extern "C" void kernel_launch(void* const* d_in, const int* in_sizes, int n_in,
                              void* d_out, int out_size, void* d_ws, size_t ws_size,
                              hipStream_t stream) {
    const float* x  = (const float*)d_in[0];
    const float* W1 = (const float*)d_in[1];
    const float* b1 = (const float*)d_in[2];
    const float* W2 = (const float*)d_in[3];
    const float* b2 = (const float*)d_in[4];
    float* out = (float*)d_out;
    char* ws = (char*)d_ws;

    ushort* a1p  = (ushort*)(ws + A1P_OFF);
    ushort* w2f  = (ushort*)(ws + W2F_OFF);
    ushort* vl   = (ushort*)(ws + VL_OFF);
    float*  c0b2 = (float*)(ws + C0_OFF);

    prep_all<<<144, 256, 0, stream>>>(W1, b1, W2, b2, a1p, w2f, vl, c0b2);
    mlp_main<<<2048, 512, 0, stream>>>(x, a1p, w2f, vl, c0b2, b1, out);
}